// Round 11
// baseline (412.219 us; speedup 1.0000x reference)
//
#include <hip/hip_runtime.h>
#include <math.h>

// VQVAE loss: total = huber_mean(x_hat - x) + 0.1 * mean_b(softDTW(x, x_hat)) + commit
// B=64, L=512, C=16, gamma=0.1, INF=1e10.
//
// Round 11 = identical resubmit of rounds 8-10 (GPU-acquisition timeouts, never ran).
// DTW restructured to 8 rows/lane, ONE WAVE PER MATRIX, zero sync.
//  - lane t owns rows 8t..8t+7; per step computes 8 chained cells at column j=s-t.
//  - cross-lane: only lane t-1's bottom row via DPP row_shr:1 + row_bcast15
//    (idiom verified exact in round 7). No LDS, no flags, no barriers.
//  - E[j][i] = kC1 * d(i,j) stored TRANSPOSED + PRE-SCALED by GEMM: per lane the
//    8 d-values are two contiguous float4 loads; 4-deep rotation in NAMED float4
//    vars (round-7 lesson: loop-carried float ARRAYS got demoted, VGPR_Count=28).
//  - scaled domain kills both softmin multiplies: kC1*kC2 == 1, so
//    cell = mv + d' - log2(1 + 2^(mv-md) + 2^(mv-mx)); subtract-first args <= 0.

#define INFS 1.0e10f
static constexpr float kC1 = 14.4269504088896f;    // log2(e)/gamma  (gamma=0.1)
static constexpr float kC2 = 0.0693147180559945f;  // gamma*ln(2); kC1*kC2 = 1

// ---------------- Huber ----------------
__device__ __forceinline__ float huber1(float d) {
  float ad = fabsf(d);
  return ad <= 1.0f ? 0.5f * d * d : ad - 0.5f;
}

__global__ __launch_bounds__(256) void huber_kernel(const float* __restrict__ x,
                                                    const float* __restrict__ xh,
                                                    float* __restrict__ part) {
  int t = threadIdx.x;
  int gid = blockIdx.x * 256 + t;
  float s = 0.f;
  for (int i = gid; i < 131072; i += 65536) {
    float4 a = ((const float4*)x)[i];
    float4 b = ((const float4*)xh)[i];
    s += huber1(b.x - a.x) + huber1(b.y - a.y) + huber1(b.z - a.z) + huber1(b.w - a.w);
  }
  for (int o = 32; o > 0; o >>= 1) s += __shfl_down(s, o, 64);
  __shared__ float ws4[4];
  if ((t & 63) == 0) ws4[t >> 6] = s;
  __syncthreads();
  if (t == 0) part[blockIdx.x] = ws4[0] + ws4[1] + ws4[2] + ws4[3];
}

// ---------------- GEMM -> transposed, pre-scaled E[j][i] = kC1 * d(i,j) ----------------
__global__ __launch_bounds__(256) void gemm_diag_kernel(const float* __restrict__ x,
                                                        const float* __restrict__ xh,
                                                        float* __restrict__ E) {
  const int b = blockIdx.z;
  const int ti = blockIdx.x;  // x-row (i) tile
  const int tj = blockIdx.y;  // xh-row (j) tile
  const int t = threadIdx.x;
  __shared__ float xsT[16 * 68];
  __shared__ float ysT[16 * 68];
  const float* xb = x + ((size_t)b * 8192) + ti * 1024;
  const float* yb = xh + ((size_t)b * 8192) + tj * 1024;
  {
    float4 xv = ((const float4*)xb)[t];
    float4 yv = ((const float4*)yb)[t];
    int r = t >> 2, c0 = (t & 3) << 2;
    xsT[(c0 + 0) * 68 + r] = xv.x;
    xsT[(c0 + 1) * 68 + r] = xv.y;
    xsT[(c0 + 2) * 68 + r] = xv.z;
    xsT[(c0 + 3) * 68 + r] = xv.w;
    ysT[(c0 + 0) * 68 + r] = yv.x;
    ysT[(c0 + 1) * 68 + r] = yv.y;
    ysT[(c0 + 2) * 68 + r] = yv.z;
    ysT[(c0 + 3) * 68 + r] = yv.w;
  }
  __syncthreads();
  const int tm = t & 15, tn = t >> 4;  // tm: i-subtile (16 x 4), tn: j-subtile (16 x 4)
  float acc[4][4] = {};
  float y2a[4] = {};
  float x2a[4] = {};
#pragma unroll
  for (int c = 0; c < 16; ++c) {
    float4 xv = *(const float4*)&xsT[c * 68 + tm * 4];
    float4 yv = *(const float4*)&ysT[c * 68 + tn * 4];
    float xr[4] = {xv.x, xv.y, xv.z, xv.w};
    float yr[4] = {yv.x, yv.y, yv.z, yv.w};
#pragma unroll
    for (int n = 0; n < 4; ++n) {
      y2a[n] = fmaf(yr[n], yr[n], y2a[n]);
#pragma unroll
      for (int m = 0; m < 4; ++m) acc[m][n] = fmaf(xr[m], yr[n], acc[m][n]);
    }
#pragma unroll
    for (int m = 0; m < 4; ++m) x2a[m] = fmaf(xr[m], xr[m], x2a[m]);
  }
  // direct coalesced stores: row j, 4 consecutive i per thread
  float* Eb = E + (size_t)b * 262144;
  const int icol = ti * 64 + tm * 4;
#pragma unroll
  for (int n = 0; n < 4; ++n) {
    int jrow = tj * 64 + tn * 4 + n;
    float4 o;
    o.x = kC1 * fmaf(-2.0f, acc[0][n], x2a[0] + y2a[n]);
    o.y = kC1 * fmaf(-2.0f, acc[1][n], x2a[1] + y2a[n]);
    o.z = kC1 * fmaf(-2.0f, acc[2][n], x2a[2] + y2a[n]);
    o.w = kC1 * fmaf(-2.0f, acc[3][n], x2a[3] + y2a[n]);
    *(float4*)&Eb[(size_t)jrow * 512 + icol] = o;
  }
}

// ---------------- DTW: 8 rows/lane, one wave per matrix, no sync ----------------
// scaled-domain cell: a=diag (i-1,j-1), b=top (i-1,j), c=left (i,j-1), d=kC1*dist
__device__ __forceinline__ float cellv(float a, float b, float c, float d) {
  float mv = fminf(fminf(a, b), c);
  float md = __builtin_amdgcn_fmed3f(a, b, c);
  float mx = fmaxf(fmaxf(a, b), c);
  float e1 = exp2f(mv - md);   // subtract first: <= 0, no overflow
  float e2 = exp2f(mv - mx);
  float lg = log2f(1.0f + e1 + e2);
  return mv + d - lg;
}

// One step: consume eL/eH slot P, update R0..R7 (chained), refill slot P for s+4.
#define STEP(P)                                                                        \
  do {                                                                                 \
    float r7old = R7;                                                                  \
    int vi7 = __float_as_int(r7old);                                                   \
    float bs = __int_as_float(__builtin_amdgcn_update_dpp(0, vi7, 0x111, 0xF, 0xF, true)); \
    float bbr = __int_as_float(__builtin_amdgcn_update_dpp(0, vi7, 0x142, 0xF, 0xF, true)); \
    float tb = fixl ? bbr : bs;                                                        \
    tb = isl0 ? INFS : tb;                                                             \
    float old0 = R0; R0 = cellv(taPrev, tb, R0, eL##P.x);                              \
    float old1 = R1; R1 = cellv(old0, R0, R1, eL##P.y);                                \
    float old2 = R2; R2 = cellv(old1, R1, R2, eL##P.z);                                \
    float old3 = R3; R3 = cellv(old2, R2, R3, eL##P.w);                                \
    float old4 = R4; R4 = cellv(old3, R3, R4, eH##P.x);                                \
    float old5 = R5; R5 = cellv(old4, R4, R5, eH##P.y);                                \
    float old6 = R6; R6 = cellv(old5, R5, R6, eH##P.z);                                \
    R7 = cellv(old6, R6, R7, eH##P.w);                                                 \
    taPrev = tb;                                                                       \
    int jn = s + 4 - t;                                                                \
    jn = jn < 0 ? 0 : (jn > 511 ? 511 : jn);                                           \
    const float4* ep = (const float4*)(baseL + ((size_t)jn << 9));                     \
    eL##P = ep[0];                                                                     \
    eH##P = ep[1];                                                                     \
    ++s;                                                                               \
  } while (0)

__global__ __launch_bounds__(64) void dtw_r8_kernel(const float* __restrict__ E,
                                                    float* __restrict__ outv) {
  const int b = blockIdx.x;
  const int t = threadIdx.x;  // lane 0..63; owns rows 8t..8t+7
  const bool isl0 = (t == 0);
  const bool fixl = ((t & 15) == 0) && (t != 0);
  const float* baseL = E + (size_t)b * 262144 + t * 8;

  // prime 4 slots (steps s=0..3): j = s - t clamped
  float4 eL0, eH0, eL1, eH1, eL2, eH2, eL3, eH3;
  {
    int j0 = 0 - t; j0 = j0 < 0 ? 0 : j0;
    int j1 = 1 - t; j1 = j1 < 0 ? 0 : j1;
    int j2 = 2 - t; j2 = j2 < 0 ? 0 : j2;
    int j3 = 3 - t; j3 = j3 < 0 ? 0 : j3;
    const float4* p0 = (const float4*)(baseL + ((size_t)j0 << 9));
    const float4* p1 = (const float4*)(baseL + ((size_t)j1 << 9));
    const float4* p2 = (const float4*)(baseL + ((size_t)j2 << 9));
    const float4* p3 = (const float4*)(baseL + ((size_t)j3 << 9));
    eL0 = p0[0]; eH0 = p0[1];
    eL1 = p1[0]; eH1 = p1[1];
    eL2 = p2[0]; eH2 = p2[1];
    eL3 = p3[0]; eH3 = p3[1];
  }

  float R0 = INFS, R1 = INFS, R2 = INFS, R3 = INFS;
  float R4 = INFS, R5 = INFS, R6 = INFS, R7 = INFS;  // column j-1 values
  float taPrev = isl0 ? 0.0f : INFS;  // (i0-1, j-1); lane0 cell(0,0) needs R(-1,-1)=0
  int s = 0;

  // 575 steps total: lane t active for s in [t, t+511]
#pragma unroll 1
  for (int it = 0; it < 143; ++it) {
    STEP(0); STEP(1); STEP(2); STEP(3);
  }
  STEP(0); STEP(1); STEP(2);  // s = 572, 573, 574

  if (t == 63) outv[b] = R7 * kC2;  // cell (511,511), de-scaled
}

// ---------------- DTW fallback (fused dot, no workspace matrix) ----------------
__device__ __forceinline__ float dot16(const float4& a, const float4& b2,
                                       const float4& c, const float4& d,
                                       const float4* yp) {
  float4 q0 = yp[0], q1 = yp[1], q2 = yp[2], q3 = yp[3];
  float s = a.x * q0.x;
  s = fmaf(a.y, q0.y, s); s = fmaf(a.z, q0.z, s); s = fmaf(a.w, q0.w, s);
  s = fmaf(b2.x, q1.x, s); s = fmaf(b2.y, q1.y, s); s = fmaf(b2.z, q1.z, s); s = fmaf(b2.w, q1.w, s);
  s = fmaf(c.x, q2.x, s); s = fmaf(c.y, q2.y, s); s = fmaf(c.z, q2.z, s); s = fmaf(c.w, q2.w, s);
  s = fmaf(d.x, q3.x, s); s = fmaf(d.y, q3.y, s); s = fmaf(d.z, q3.z, s); s = fmaf(d.w, q3.w, s);
  return s;
}

#define DTW_FSTEP(W, R1v, R2v)                                              \
  do {                                                                      \
    int j = k - tid;                                                        \
    bool valid = (j >= 0) && (j < 512);                                     \
    int jc = valid ? j : 0;                                                 \
    float av = R2v[tid];                                                    \
    float bv = R1v[tid];                                                    \
    float dotv = dot16(xa, xb4, xc4, xd4, (const float4*)&ysl[jc * 20]);    \
    float mv = fminf(fminf(av, bv), vprev);                                 \
    float ssum = exp2f((mv - av) * kC1) + exp2f((mv - bv) * kC1) +          \
                 exp2f((mv - vprev) * kC1);                                 \
    float sm3 = fmaf(-kC2, log2f(ssum), mv);                                \
    float dd = fmaf(-2.0f, dotv, x2 + y2s[jc]);                             \
    float val = valid ? (dd + sm3) : INFS;                                  \
    W[tid + 1] = val;                                                       \
    vprev = val;                                                            \
    __syncthreads();                                                        \
    ++k;                                                                    \
  } while (0)

__global__ __launch_bounds__(512) void dtw_fused_kernel(const float* __restrict__ x,
                                                        const float* __restrict__ xh,
                                                        float* __restrict__ outv) {
  const int b = blockIdx.x;
  const int tid = threadIdx.x;
  __shared__ float ysl[512 * 20];
  __shared__ float y2s[512];
  __shared__ float rA[516], rB[516], rC[516];
  const float* xr = x + (size_t)b * 8192 + tid * 16;
  const float* yr = xh + (size_t)b * 8192 + tid * 16;
  float4 xa = *(const float4*)(xr + 0);
  float4 xb4 = *(const float4*)(xr + 4);
  float4 xc4 = *(const float4*)(xr + 8);
  float4 xd4 = *(const float4*)(xr + 12);
  float x2 = xa.x * xa.x + xa.y * xa.y + xa.z * xa.z + xa.w * xa.w +
             xb4.x * xb4.x + xb4.y * xb4.y + xb4.z * xb4.z + xb4.w * xb4.w +
             xc4.x * xc4.x + xc4.y * xc4.y + xc4.z * xc4.z + xc4.w * xc4.w +
             xd4.x * xd4.x + xd4.y * xd4.y + xd4.z * xd4.z + xd4.w * xd4.w;
  {
    float4 q0 = *(const float4*)(yr + 0);
    float4 q1 = *(const float4*)(yr + 4);
    float4 q2 = *(const float4*)(yr + 8);
    float4 q3 = *(const float4*)(yr + 12);
    *(float4*)&ysl[tid * 20 + 0] = q0;
    *(float4*)&ysl[tid * 20 + 4] = q1;
    *(float4*)&ysl[tid * 20 + 8] = q2;
    *(float4*)&ysl[tid * 20 + 12] = q3;
    y2s[tid] = q0.x * q0.x + q0.y * q0.y + q0.z * q0.z + q0.w * q0.w +
               q1.x * q1.x + q1.y * q1.y + q1.z * q1.z + q1.w * q1.w +
               q2.x * q2.x + q2.y * q2.y + q2.z * q2.z + q2.w * q2.w +
               q3.x * q3.x + q3.y * q3.y + q3.z * q3.z + q3.w * q3.w;
  }
  rA[tid] = INFS;
  rB[tid] = INFS;
  rC[tid] = INFS;
  if (tid == 0) { rA[512] = INFS; rB[512] = INFS; rC[512] = INFS; }
  __syncthreads();
  float dot00 = dot16(xa, xb4, xc4, xd4, (const float4*)&ysl[0]);
  float d00 = fmaf(-2.0f, dot00, x2 + y2s[0]);
  float vprev = (tid == 0) ? d00 : INFS;
  if (tid == 0) rC[1] = d00;
  int k = 1;
  __syncthreads();
#pragma unroll 1
  for (int it = 0; it < 340; ++it) {
    DTW_FSTEP(rA, rC, rB);
    DTW_FSTEP(rB, rA, rC);
    DTW_FSTEP(rC, rB, rA);
  }
  DTW_FSTEP(rA, rC, rB);
  DTW_FSTEP(rB, rA, rC);
  if (tid == 511) outv[b] = vprev;
}

// ---------------- finalize ----------------
__global__ __launch_bounds__(256) void finalize_kernel(const float* __restrict__ part,
                                                       const float* __restrict__ dtwv,
                                                       const float* __restrict__ commit,
                                                       float* __restrict__ out) {
  int t = threadIdx.x;
  float h = part[t];
  float dv = (t < 64) ? dtwv[t] : 0.f;
  for (int o = 32; o > 0; o >>= 1) {
    h += __shfl_down(h, o, 64);
    dv += __shfl_down(dv, o, 64);
  }
  __shared__ float sh[4], sd[4];
  if ((t & 63) == 0) { sh[t >> 6] = h; sd[t >> 6] = dv; }
  __syncthreads();
  if (t == 0) {
    float hs = sh[0] + sh[1] + sh[2] + sh[3];
    float ds = sd[0] + sd[1] + sd[2] + sd[3];
    float hm = hs * (1.0f / 524288.0f);
    float smv = ds * (0.1f / 64.0f);
    float cm = commit[0];
    out[0] = hm + smv + cm;
    out[1] = hm;
    out[2] = smv;
    out[3] = cm;
  }
}

extern "C" void kernel_launch(void* const* d_in, const int* in_sizes, int n_in,
                              void* d_out, int out_size, void* d_ws, size_t ws_size,
                              hipStream_t stream) {
  (void)in_sizes; (void)n_in; (void)out_size;
  const float* x = (const float*)d_in[0];
  const float* xh = (const float*)d_in[1];
  const float* commit = (const float*)d_in[2];
  float* out = (float*)d_out;
  float* ws = (float*)d_ws;
  float* part = ws;        // 256 floats
  float* dtwv = ws + 256;  // 64 floats
  float* E = ws + 512;     // 64 * 262144 floats: E[b][j][i] = kC1*d(i,j)
  const size_t need = 2048 + (size_t)64 * 262144 * 4;

  huber_kernel<<<256, 256, 0, stream>>>(x, xh, part);
  if (ws_size >= need) {
    gemm_diag_kernel<<<dim3(8, 8, 64), 256, 0, stream>>>(x, xh, E);
    dtw_r8_kernel<<<64, 64, 0, stream>>>(E, dtwv);
  } else {
    dtw_fused_kernel<<<64, 512, 0, stream>>>(x, xh, dtwv);
  }
  finalize_kernel<<<1, 256, 0, stream>>>(part, dtwv, commit, out);
}